// Round 7
// baseline (34.071 us; speedup 1.0000x reference)
//
#include <hip/hip_runtime.h>
#include <math.h>

#define PI_F 3.14159265358979323846f

typedef float f32x4 __attribute__((ext_vector_type(4)));
typedef int   i32x2 __attribute__((ext_vector_type(2)));

// ---------------------------------------------------------------------------
// Cross-lane exchange primitives (hardware-verified R5/R6).
// dpp ctrl: quad_perm[1,0,3,2]=0xB1 (xor1), [2,3,0,1]=0x4E (xor2),
//           [3,2,1,0]=0x1B (xor3), row_half_mirror=0x141 (xor7),
//           row_ror:8=0x128 (xor8).
// ds_swizzle BitMode offset = (xor<<10)|(or<<5)|and.
// ---------------------------------------------------------------------------
template<int CTRL>
static __device__ __forceinline__ float dppf(float v) {
  return __builtin_bit_cast(float,
    __builtin_amdgcn_update_dpp(0, __builtin_bit_cast(int, v), CTRL, 0xF, 0xF, false));
}
template<int OFF>
static __device__ __forceinline__ float swzf(float v) {
  return __builtin_bit_cast(float,
    __builtin_amdgcn_ds_swizzle(__builtin_bit_cast(int, v), OFF));
}
static __device__ __forceinline__ float pswap32(float v, bool hi) {
  // v_permlane32_swap_b32: with both operands = v,
  // r.x[l>=32]=v[l-32]; r.y[l<32]=v[l+32]. xor32: lanes<32 take r.y,
  // lanes>=32 take r.x.  (verified R5)
  i32x2 r = __builtin_amdgcn_permlane32_swap(
      __builtin_bit_cast(int, v), __builtin_bit_cast(int, v), false, false);
  return __builtin_bit_cast(float, hi ? r.x : r.y);
}

template<int MASK>
static __device__ __forceinline__ float lxor(float v, bool hi32) {
  if constexpr (MASK == 1)       return dppf<0xB1>(v);
  else if constexpr (MASK == 2)  return dppf<0x4E>(v);
  else if constexpr (MASK == 3)  return dppf<0x1B>(v);
  else if constexpr (MASK == 4)  return dppf<0x1B>(dppf<0x141>(v));   // 7^3
  else if constexpr (MASK == 6)  return dppf<0xB1>(dppf<0x141>(v));   // 7^1
  else if constexpr (MASK == 8)  return dppf<0x128>(v);
  else if constexpr (MASK == 12) return swzf<0x301F>(v);
  else if constexpr (MASK == 16) return swzf<0x401F>(v);
  else if constexpr (MASK == 24) return swzf<0x401F>(dppf<0x128>(v));
  else if constexpr (MASK == 32) return pswap32(v, hi32);
  else if constexpr (MASK == 48) return swzf<0x401F>(pswap32(v, hi32));
  else return __shfl_xor(v, MASK, 64);
}
// wave-uniform broadcast from lane SRC (valid after full 64-lane reduce)
template<int SRC>
static __device__ __forceinline__ float bswzf(float v) { return swzf<(SRC<<5)>(v); }

static __device__ __forceinline__ float xorsgn(float v, int sgn) {
  return __builtin_bit_cast(float, __builtin_bit_cast(int, v) ^ sgn);
}

// ---------------------------------------------------------------------------
// Index algebra identical to R2..R6 (verified): amplitude p = lane*4 + r,
// wires 0..5 = lane bits 5..0, wires 6,7 = r bits 1,0. CNOTs absorbed into
// gate masks via GF(2) relabeling (A1/A2).
// Rot structure: u11 = conj(u00), u10 = -conj(u01) =>
//   coefficients (Ar, ±S, ±T, Bi) with S=u00i^plsgn, T=u01r^plsgn;
//   r-parity sign folded into compile-time fma sign.
// ---------------------------------------------------------------------------
template<int R, int LMASK, int RMASK, int HIR>
static __device__ __forceinline__ void gate_step(
    const float ar[4], const float ai[4], float& nr, float& ni,
    float Ar, float S, float T, float Bi, bool hi32)
{
  constexpr int  rx = R & HIR;
  constexpr bool RP = (rx == 1 || rx == 2);   // parity of 2-bit value
  const float sr = ar[R], si = ai[R];
  float pr, pi;
  if constexpr (LMASK != 0) {
    pr = lxor<LMASK>(ar[R ^ RMASK], hi32);
    pi = lxor<LMASK>(ai[R ^ RMASK], hi32);
  } else {
    pr = ar[R ^ RMASK]; pi = ai[R ^ RMASK];
  }
  float t = Ar * sr;
  if constexpr (!RP) t = fmaf(-S, si, t); else t = fmaf(S, si, t);
  if constexpr (!RP) t = fmaf( T, pr, t); else t = fmaf(-T, pr, t);
  t = fmaf(-Bi, pi, t);
  nr = t;
  t = Ar * si;
  if constexpr (!RP) t = fmaf(S, sr, t); else t = fmaf(-S, sr, t);
  if constexpr (!RP) t = fmaf(T, pi, t); else t = fmaf(-T, pi, t);
  t = fmaf(Bi, pr, t);
  ni = t;
}

template<int LMASK, int RMASK, int HIL, int HIR>
static __device__ __forceinline__ void applyG(float ar[4], float ai[4],
    const f32x4* __restrict__ g4, int lane, bool hi32)
{
  const f32x4 g = *g4;        // u00r, u00i, u01r, u01i
  const float Ar = g.x, Bi = g.w;
  float S = g.y, T = g.z;
  if constexpr (HIL != 0) {
    const int sgn = (__popc(lane & HIL) & 1) << 31;
    S = xorsgn(S, sgn);
    T = xorsgn(T, sgn);
  }
  float nr[4], ni[4];
  gate_step<0, LMASK, RMASK, HIR>(ar, ai, nr[0], ni[0], Ar, S, T, Bi, hi32);
  gate_step<1, LMASK, RMASK, HIR>(ar, ai, nr[1], ni[1], Ar, S, T, Bi, hi32);
  gate_step<2, LMASK, RMASK, HIR>(ar, ai, nr[2], ni[2], Ar, S, T, Bi, hi32);
  gate_step<3, LMASK, RMASK, HIR>(ar, ai, nr[3], ni[3], Ar, S, T, Bi, hi32);
#pragma unroll
  for (int r = 0; r < 4; ++r) { ar[r] = nr[r]; ai[r] = ni[r]; }
}

// ---------------------------------------------------------------------------
// Setup: 16 Rot gates -> 4 floats each: u00r, u00i, u01r, u01i
// ---------------------------------------------------------------------------
__global__ void qbranch_setup(const float* __restrict__ weights,
                              float* __restrict__ gates)
{
  int t = threadIdx.x;
  if (t >= 16) return;
  float phi = weights[t*3 + 0];
  float th  = weights[t*3 + 1];
  float om  = weights[t*3 + 2];
  float ct = cosf(th * 0.5f), st = sinf(th * 0.5f);
  float ap = (phi + om) * 0.5f, am = (phi - om) * 0.5f;
  float* g = gates + t*4;
  g[0] =  cosf(ap)*ct;   // u00r
  g[1] = -sinf(ap)*ct;   // u00i
  g[2] = -cosf(am)*st;   // u01r
  g[3] = -sinf(am)*st;   // u01i
}

// ---------------------------------------------------------------------------
// Main: 4 waves/block, ONE batch element per wave, scalar math.
// __launch_bounds__(256,8): force VGPR<=64 so 32 waves/CU stay resident.
// ---------------------------------------------------------------------------
__global__ __launch_bounds__(256, 8) void qbranch_main(
    const float* __restrict__ x,     // (B,8)
    const float* __restrict__ gates, // 16 gates x 4 floats
    const float* __restrict__ Wm,    // (8,64)
    const float* __restrict__ bias,  // (64)
    const float* __restrict__ gamma, // (64)
    const float* __restrict__ beta,  // (64)
    float* __restrict__ out,         // (B,64)
    int B)
{
  const int lane = threadIdx.x & 63;
  const int wid  = threadIdx.x >> 6;
  const int b    = blockIdx.x * 4 + wid;
  if (b >= B) return;
  const bool hi32 = lane >= 32;

  // --- trig on lanes 0..15: lane 2w -> cos_w, lane 2w+1 -> sin_w ----------
  float val = 0.f;
  if (lane < 16) {
    float xv = x[b*8 + (lane >> 1)];
    float th = 1.f - 2.f / (__expf(2.f*xv) + 1.f);   // tanh
    float ha = th * (PI_F * 0.5f);
    val = (lane & 1) ? __sinf(ha) : __cosf(ha);
  }

  const int l5=(lane>>5)&1, l4=(lane>>4)&1, l3=(lane>>3)&1,
            l2=(lane>>2)&1, l1=(lane>>1)&1, l0=lane&1;
  float m0 = __shfl(val,  0 + l5, 64);
  float m1 = __shfl(val,  2 + l4, 64);
  float m2 = __shfl(val,  4 + l3, 64);
  float m3 = __shfl(val,  6 + l2, 64);
  float m4 = __shfl(val,  8 + l1, 64);
  float m5 = __shfl(val, 10 + l0, 64);
  float c6 = __shfl(val, 12, 64), s6 = __shfl(val, 13, 64);
  float c7 = __shfl(val, 14, 64), s7 = __shfl(val, 15, 64);

  const float p6 = m0*m1*m2*m3*m4*m5;

  // product state: amp(p) = mag(p) * (-i)^popc(p)
  float ar[4], ai[4];
  {
    const float mag[4] = { p6*c6*c7, p6*c6*s7, p6*s6*c7, p6*s6*s7 };
    const int kl = __popc(lane);
#pragma unroll
    for (int r = 0; r < 4; ++r) {
      const int k = kl + ((r >> 1) & 1) + (r & 1);
      float sgn = (k & 2) ? -mag[r] : mag[r];
      ar[r] = (k & 1) ? 0.f : sgn;
      ai[r] = (k & 1) ? -sgn : 0.f;
    }
  }

  const f32x4* G = (const f32x4*)gates;

  // --- layer 0 Rot gates (A = I) ------------------------------------------
  applyG<0x20, 0, 0x20, 0>(ar, ai, G +  0, lane, hi32);
  applyG<0x10, 0, 0x10, 0>(ar, ai, G +  1, lane, hi32);
  applyG<0x08, 0, 0x08, 0>(ar, ai, G +  2, lane, hi32);
  applyG<0x04, 0, 0x04, 0>(ar, ai, G +  3, lane, hi32);
  applyG<0x02, 0, 0x02, 0>(ar, ai, G +  4, lane, hi32);
  applyG<0x01, 0, 0x01, 0>(ar, ai, G +  5, lane, hi32);
  applyG<0x00, 2, 0x00, 2>(ar, ai, G +  6, lane, hi32);
  applyG<0x00, 1, 0x00, 1>(ar, ai, G +  7, lane, hi32);

  // --- layer 1 Rot gates (CNOT ring r=1 absorbed) -------------------------
  applyG<0x30, 0, 0x1F, 3>(ar, ai, G +  8, lane, hi32);
  applyG<0x18, 0, 0x30, 0>(ar, ai, G +  9, lane, hi32);
  applyG<0x0C, 0, 0x38, 0>(ar, ai, G + 10, lane, hi32);
  applyG<0x06, 0, 0x3C, 0>(ar, ai, G + 11, lane, hi32);
  applyG<0x03, 0, 0x3E, 0>(ar, ai, G + 12, lane, hi32);
  applyG<0x01, 2, 0x3F, 0>(ar, ai, G + 13, lane, hi32);
  applyG<0x00, 3, 0x3F, 2>(ar, ai, G + 14, lane, hi32);
  applyG<0x30, 1, 0x3F, 3>(ar, ai, G + 15, lane, hi32);

  // --- Z expectations with A2 sign masks ----------------------------------
  const float pp0 = fmaf(ar[0], ar[0], ai[0]*ai[0]);
  const float pp1 = fmaf(ar[1], ar[1], ai[1]*ai[1]);
  const float pp2 = fmaf(ar[2], ar[2], ai[2]*ai[2]);
  const float pp3 = fmaf(ar[3], ar[3], ai[3]*ai[3]);
  const float s01 = pp0 + pp1, d01 = pp0 - pp1;
  const float s23 = pp2 + pp3, d23 = pp2 - pp3;
  const float q0 = s01 + s23;
  const float q1 = d01 + d23;
  const float q2 = s01 - s23;
  const float q3 = d01 - d23;
  const float n0 = -q0, n1 = -q1, n2 = -q2, n3 = -q3;

  float zp[8];
  zp[0] = (__popc(lane & 0x39) & 1) ? n2 : q2;
  zp[1] = (__popc(lane & 0x3C) & 1) ? n3 : q3;
  zp[2] = (__popc(lane & 0x27) & 1) ? n3 : q3;
  zp[3] = (__popc(lane & 0x0C) & 1) ? n0 : q0;
  zp[4] = (__popc(lane & 0x19) & 1) ? n3 : q3;
  zp[5] = (__popc(lane & 0x33) & 1) ? n0 : q0;
  zp[6] = (__popc(lane & 0x26) & 1) ? n1 : q1;
  zp[7] = (__popc(lane & 0x0C) & 1) ? n3 : q3;

  // --- split-butterfly reduce: lane ends with z_{4*b0+2*b1+b2} ------------
  const bool lb0 = (lane & 1) != 0, lb1 = (lane & 2) != 0, lb2 = (lane & 4) != 0;
  float u[4];
#pragma unroll
  for (int k = 0; k < 4; ++k) {
    float snd = lb0 ? zp[k] : zp[k+4];
    float rcv = lxor<1>(snd, hi32);
    u[k] = (lb0 ? zp[k+4] : zp[k]) + rcv;
  }
  float v2[2];
#pragma unroll
  for (int k = 0; k < 2; ++k) {
    float snd = lb1 ? u[k] : u[k+2];
    float rcv = lxor<2>(snd, hi32);
    v2[k] = (lb1 ? u[k+2] : u[k]) + rcv;
  }
  float snd3 = lb2 ? v2[0] : v2[1];
  float zs = (lb2 ? v2[1] : v2[0]) + lxor<4>(snd3, hi32);
  zs += lxor< 8>(zs, hi32);
  zs += lxor<16>(zs, hi32);
  zs += lxor<32>(zs, hi32);

  const float z0 = bswzf<0>(zs);
  const float z1 = bswzf<4>(zs);
  const float z2 = bswzf<2>(zs);
  const float z3 = bswzf<6>(zs);
  const float z4 = bswzf<1>(zs);
  const float z5 = bswzf<5>(zs);
  const float z6 = bswzf<3>(zs);
  const float z7 = bswzf<7>(zs);

  // --- projection (8 -> 64), lane j computes h[j] --------------------------
  const int j = lane;
  float h = bias[j];
  h = fmaf(z0, Wm[0*64 + j], h);
  h = fmaf(z1, Wm[1*64 + j], h);
  h = fmaf(z2, Wm[2*64 + j], h);
  h = fmaf(z3, Wm[3*64 + j], h);
  h = fmaf(z4, Wm[4*64 + j], h);
  h = fmaf(z5, Wm[5*64 + j], h);
  h = fmaf(z6, Wm[6*64 + j], h);
  h = fmaf(z7, Wm[7*64 + j], h);

  // --- LayerNorm: fused sum/sumsq butterfly -------------------------------
  float S = h, Q = h*h;
  float snd4 = lb0 ? S : Q;
  float acc = (lb0 ? Q : S) + lxor<1>(snd4, hi32);
  acc += lxor< 2>(acc, hi32);
  acc += lxor< 4>(acc, hi32);
  acc += lxor< 8>(acc, hi32);
  acc += lxor<16>(acc, hi32);
  acc += lxor<32>(acc, hi32);
  const float Ssum = bswzf<0>(acc);
  const float Qsum = bswzf<1>(acc);
  const float mu  = Ssum * (1.f/64.f);
  const float var = fmaf(-mu, mu, Qsum * (1.f/64.f));

  out[b*64 + j] = fmaf(gamma[j] * (h - mu), rsqrtf(var + 1e-5f), beta[j]);
}

// ---------------------------------------------------------------------------
extern "C" void kernel_launch(void* const* d_in, const int* in_sizes, int n_in,
                              void* d_out, int out_size, void* d_ws, size_t ws_size,
                              hipStream_t stream)
{
  const float* x       = (const float*)d_in[0];
  const float* weights = (const float*)d_in[1];
  const float* Wm      = (const float*)d_in[2];
  const float* bias    = (const float*)d_in[3];
  const float* gamma   = (const float*)d_in[4];
  const float* beta    = (const float*)d_in[5];
  float* out   = (float*)d_out;
  float* gates = (float*)d_ws;   // 16 gates * 4 floats

  const int B = in_sizes[0] / 8;

  hipLaunchKernelGGL(qbranch_setup, dim3(1), dim3(64), 0, stream, weights, gates);
  hipLaunchKernelGGL(qbranch_main, dim3((B + 3) / 4), dim3(256), 0, stream,
                     x, gates, Wm, bias, gamma, beta, out, B);
}